// Round 4
// baseline (236.213 us; speedup 1.0000x reference)
//
#include <hip/hip_runtime.h>
#include <math.h>

typedef _Float16 half_t;
typedef __attribute__((ext_vector_type(8))) _Float16 half8;
typedef __attribute__((ext_vector_type(4))) _Float16 half4;
typedef __attribute__((ext_vector_type(2))) _Float16 half2v;
typedef __attribute__((ext_vector_type(4))) float floatx4;

#define BATCH   8
#define SEQ     4096
#define DM      512
#define NP      256
#define M_TOT   32768
#define NTOT    768
#define CHUNKS  128
#define CHUNK_LEN 32

__device__ __forceinline__ void async_load16(const void* g, void* l) {
    __builtin_amdgcn_global_load_lds((const __attribute__((address_space(1))) void*)g,
                                     (__attribute__((address_space(3))) void*)l,
                                     16, 0, 0);
}

// ---------------------------------------------------------------------------
// decay[m] = sigmoid(dot(X[m,:], Wd) + bd), fused with x fp32->fp16 convert.
// One wave per row; 32B contiguous read + one 16B half8 store per lane.
// ---------------------------------------------------------------------------
__global__ __launch_bounds__(256) void decay_convert(const float* __restrict__ X,
                                                     const float* __restrict__ Wd,
                                                     const float* __restrict__ bd,
                                                     float* __restrict__ dec,
                                                     half_t* __restrict__ Xh) {
    const int wave = threadIdx.x >> 6;
    const int lane = threadIdx.x & 63;
    const int row  = blockIdx.x * 4 + wave;
    const float4* xr = (const float4*)(X + (size_t)row * DM);
    const float4* wd = (const float4*)Wd;
    float4 v0 = xr[2 * lane], v1 = xr[2 * lane + 1];
    float4 w0 = wd[2 * lane], w1 = wd[2 * lane + 1];
    float sum = v0.x * w0.x + v0.y * w0.y + v0.z * w0.z + v0.w * w0.w
              + v1.x * w1.x + v1.y * w1.y + v1.z * w1.z + v1.w * w1.w;
    half8 h = {(half_t)v0.x, (half_t)v0.y, (half_t)v0.z, (half_t)v0.w,
               (half_t)v1.x, (half_t)v1.y, (half_t)v1.z, (half_t)v1.w};
    *(half8*)(Xh + (size_t)row * DM + lane * 8) = h;
#pragma unroll
    for (int off = 32; off > 0; off >>= 1) sum += __shfl_down(sum, off, 64);
    if (lane == 0) {
        float z = sum + bd[0];
        dec[row] = 1.0f / (1.0f + __expf(-z));
    }
}

// ---------------------------------------------------------------------------
// Wcat_t[768][512] fp16 = [Wi^T ; Wa^T]
// ---------------------------------------------------------------------------
__global__ __launch_bounds__(256) void wcat_transpose(const float* __restrict__ Wi,
                                                      const float* __restrict__ Wa,
                                                      half_t* __restrict__ Wt) {
    const int idx = blockIdx.x * 256 + threadIdx.x;
    const int n = idx >> 9;
    const int k = idx & 511;
    float v = (n < DM) ? Wi[(size_t)k * DM + n] : Wa[(size_t)k * NP + (n - DM)];
    Wt[idx] = (half_t)v;
}

// ---------------------------------------------------------------------------
// Fused MFMA GEMM, effective BK=64: two 8KB buffers per operand (each the
// proven conflict-free BK=32 XOR-swizzled layout) loaded before one barrier;
// 32 MFMAs per barrier pair, 8 K-iterations.
// ---------------------------------------------------------------------------
__global__ __launch_bounds__(256) void gemm_fused(const half_t* __restrict__ Xh,
                                                  const half_t* __restrict__ Wt,
                                                  const float* __restrict__ bi,
                                                  const float* __restrict__ ba,
                                                  float* __restrict__ out,
                                                  half_t* __restrict__ angles) {
    __shared__ __align__(16) char As[2][8192];
    __shared__ __align__(16) char Bs[2][8192];

    const int bm   = blockIdx.x;
    const int bn   = blockIdx.y;
    const int tid  = threadIdx.x;
    const int wave = tid >> 6;
    const int lane = tid & 63;
    const int quad = lane >> 4;
    const int l16  = lane & 15;
    const int wrow = wave >> 1;
    const int wcol = wave & 1;

    floatx4 acc[4][4];
#pragma unroll
    for (int i = 0; i < 4; ++i)
#pragma unroll
        for (int j = 0; j < 4; ++j) acc[i][j] = (floatx4){0.f, 0.f, 0.f, 0.f};

    const int s0 = wave * 128 + lane;
    const int s1 = s0 + 64;
    const int r0 = s0 >> 2, kql0 = (s0 & 3) ^ ((r0 >> 1) & 3);
    const int r1 = s1 >> 2, kql1 = (s1 & 3) ^ ((r1 >> 1) & 3);
    const half_t* gA0 = Xh + (size_t)(bm * 128 + r0) * DM + kql0 * 8;
    const half_t* gA1 = Xh + (size_t)(bm * 128 + r1) * DM + kql1 * 8;
    const half_t* gB0 = Wt + (size_t)(bn * 128 + r0) * DM + kql0 * 8;
    const half_t* gB1 = Wt + (size_t)(bn * 128 + r1) * DM + kql1 * 8;

    for (int k0 = 0; k0 < DM; k0 += 64) {
#pragma unroll
        for (int kb = 0; kb < 2; ++kb) {
            const int ko = k0 + kb * 32;
            async_load16(gA0 + ko, As[kb] + wave * 2048);
            async_load16(gA1 + ko, As[kb] + wave * 2048 + 1024);
            async_load16(gB0 + ko, Bs[kb] + wave * 2048);
            async_load16(gB1 + ko, Bs[kb] + wave * 2048 + 1024);
        }
        __syncthreads();

#pragma unroll
        for (int kb = 0; kb < 2; ++kb) {
            half8 af[4], bf[4];
#pragma unroll
            for (int mt = 0; mt < 4; ++mt) {
                const int r = wrow * 64 + mt * 16 + l16;
                af[mt] = *(const half8*)(As[kb] + r * 64 + ((quad ^ ((r >> 1) & 3)) << 4));
            }
#pragma unroll
            for (int nt = 0; nt < 4; ++nt) {
                const int r = wcol * 64 + nt * 16 + l16;
                bf[nt] = *(const half8*)(Bs[kb] + r * 64 + ((quad ^ ((r >> 1) & 3)) << 4));
            }
#pragma unroll
            for (int mt = 0; mt < 4; ++mt)
#pragma unroll
                for (int nt = 0; nt < 4; ++nt)
                    acc[mt][nt] = __builtin_amdgcn_mfma_f32_16x16x32_f16(af[mt], bf[nt],
                                                                         acc[mt][nt], 0, 0, 0);
        }
        __syncthreads();
    }

    const int colbase = bn * 128 + wcol * 64;
#pragma unroll
    for (int nt = 0; nt < 4; ++nt) {
        const int col = colbase + nt * 16 + l16;
        const bool is_inj = col < DM;
        const float bias = is_inj ? bi[col] : ba[col - DM];
#pragma unroll
        for (int mt = 0; mt < 4; ++mt) {
            const int rowb = bm * 128 + wrow * 64 + mt * 16 + quad * 4;
#pragma unroll
            for (int r = 0; r < 4; ++r) {
                const float v = acc[mt][nt][r] + bias;
                const int row = rowb + r;
                if (is_inj) out[(size_t)row * DM + col] = v;
                else        angles[(size_t)row * NP + (col - DM)] = (half_t)v;
            }
        }
    }
}

// ---------------------------------------------------------------------------
// sum1: per-chunk summaries only (no state writes). Thread = 2 pairs,
// block = 2 chunks (threads 0-127 chunk c, 128-255 chunk c+1).
// ---------------------------------------------------------------------------
__global__ __launch_bounds__(256) void scan_sum1(const half_t* __restrict__ angles,
                                                 const float* __restrict__ decays,
                                                 const float* __restrict__ inj,
                                                 float* __restrict__ thetaC,
                                                 float4* __restrict__ hend,
                                                 float* __restrict__ Dprod) {
    const int b    = blockIdx.x >> 6;
    const int sub  = threadIdx.x >> 7;
    const int th   = threadIdx.x & 127;
    const int c    = (blockIdx.x & 63) * 2 + sub;
    const int p0   = th * 2;
    const int t0   = c * CHUNK_LEN;
    const float4* inj4 = (const float4*)inj;

    float h0a = 0, h1a = 0, h0b = 0, h1b = 0, tha = 0, thb = 0, dc = 1.0f;
#pragma unroll 4
    for (int i = 0; i < CHUNK_LEN; ++i) {
        const int t = t0 + i;
        const size_t base = (size_t)(b * SEQ + t) * NP + p0;
        half2v av = *(const half2v*)(angles + base);
        float4 u = inj4[base >> 1];
        float d = decays[b * SEQ + t];
        float a0 = (float)av[0], a1 = (float)av[1];
        float s0, c0, s1, c1;
        __sincosf(a0, &s0, &c0);
        __sincosf(a1, &s1, &c1);
        float n0a = fmaf(d, c0 * h0a - s0 * h1a, u.x);
        float n1a = fmaf(d, s0 * h0a + c0 * h1a, u.y);
        float n0b = fmaf(d, c1 * h0b - s1 * h1b, u.z);
        float n1b = fmaf(d, s1 * h0b + c1 * h1b, u.w);
        h0a = n0a; h1a = n1a; h0b = n0b; h1b = n1b;
        tha += a0; thb += a1; dc *= d;
    }
    const size_t cbase = (size_t)(b * CHUNKS + c) * NP + p0;
    *(float2*)(thetaC + cbase) = make_float2(tha, thb);
    hend[cbase >> 1] = make_float4(h0a, h1a, h0b, h1b);
    if (th == 0) Dprod[b * CHUNKS + c] = dc;
}

// ---------------------------------------------------------------------------
// chunk-operator scan: 8 blocks x 128 threads, 2 pairs/thread.
// ---------------------------------------------------------------------------
__global__ __launch_bounds__(128) void scan_chunks(const float* __restrict__ thetaC,
                                                   const float4* __restrict__ hend,
                                                   const float* __restrict__ Dprod,
                                                   float4* __restrict__ hentry) {
    const int b  = blockIdx.x;
    const int p0 = threadIdx.x * 2;
    float h0a = 0, h1a = 0, h0b = 0, h1b = 0;
    for (int c = 0; c < CHUNKS; ++c) {
        const size_t cbase = (size_t)(b * CHUNKS + c) * NP + p0;
        hentry[cbase >> 1] = make_float4(h0a, h1a, h0b, h1b);
        float2 th2 = *(const float2*)(thetaC + cbase);
        float D = Dprod[b * CHUNKS + c];
        float4 he = hend[cbase >> 1];
        float s0, c0, s1, c1;
        __sincosf(th2.x, &s0, &c0);
        __sincosf(th2.y, &s1, &c1);
        float n0a = fmaf(D, c0 * h0a - s0 * h1a, he.x);
        float n1a = fmaf(D, s0 * h0a + c0 * h1a, he.y);
        float n0b = fmaf(D, c1 * h0b - s1 * h1b, he.z);
        float n1b = fmaf(D, s1 * h0b + c1 * h1b, he.w);
        h0a = n0a; h1a = n1a; h0b = n0b; h1b = n1b;
    }
}

// ---------------------------------------------------------------------------
// final: redo local scan seeded with chunk entry state; write final states.
// ---------------------------------------------------------------------------
__global__ __launch_bounds__(256) void scan_final(const half_t* __restrict__ angles,
                                                  const float* __restrict__ decays,
                                                  const float4* __restrict__ hentry,
                                                  float* __restrict__ out) {
    const int b    = blockIdx.x >> 6;
    const int sub  = threadIdx.x >> 7;
    const int th   = threadIdx.x & 127;
    const int c    = (blockIdx.x & 63) * 2 + sub;
    const int p0   = th * 2;
    const int t0   = c * CHUNK_LEN;
    float4* out4 = (float4*)out;

    float4 v = hentry[((size_t)(b * CHUNKS + c) * NP + p0) >> 1];
    float h0a = v.x, h1a = v.y, h0b = v.z, h1b = v.w;
#pragma unroll 4
    for (int i = 0; i < CHUNK_LEN; ++i) {
        const int t = t0 + i;
        const size_t base = (size_t)(b * SEQ + t) * NP + p0;
        half2v av = *(const half2v*)(angles + base);
        float4 u = out4[base >> 1];
        float d = decays[b * SEQ + t];
        float a0 = (float)av[0], a1 = (float)av[1];
        float s0, c0, s1, c1;
        __sincosf(a0, &s0, &c0);
        __sincosf(a1, &s1, &c1);
        float n0a = fmaf(d, c0 * h0a - s0 * h1a, u.x);
        float n1a = fmaf(d, s0 * h0a + c0 * h1a, u.y);
        float n0b = fmaf(d, c1 * h0b - s1 * h1b, u.z);
        float n1b = fmaf(d, s1 * h0b + c1 * h1b, u.w);
        h0a = n0a; h1a = n1a; h0b = n0b; h1b = n1b;
        out4[base >> 1] = make_float4(h0a, h1a, h0b, h1b);
    }
}

// ---------------------------------------------------------------------------
extern "C" void kernel_launch(void* const* d_in, const int* in_sizes, int n_in,
                              void* d_out, int out_size, void* d_ws, size_t ws_size,
                              hipStream_t stream) {
    const float* x  = (const float*)d_in[0];
    const float* Wa = (const float*)d_in[1];
    const float* ba = (const float*)d_in[2];
    const float* Wd = (const float*)d_in[3];
    const float* bd = (const float*)d_in[4];
    const float* Wi = (const float*)d_in[5];
    const float* bi = (const float*)d_in[6];
    float* out = (float*)d_out;

    char* ws = (char*)d_ws;
    // x_h dead after gemm_fused; scan scratch overlays it.
    half_t* x_h     = (half_t*)(ws);                  // 33,554,432 B @ 0
    float*  thetaC  = (float*)(ws);                   //  1,048,576 B @ 0        (overlay)
    float4* hend    = (float4*)(ws + 1048576);        //  2,097,152 B            (overlay)
    float*  Dprod   = (float*)(ws + 3145728);         //      4,096 B            (overlay)
    float4* hentry  = (float4*)(ws + 3149824);        //  2,097,152 B            (overlay)
    half_t* angles  = (half_t*)(ws + 33554432);       // 16,777,216 B
    float*  decays  = (float*)(ws + 50331648);        //    131,072 B
    half_t* Wcat_t  = (half_t*)(ws + 50462720);       //    786,432 B
    // total: 51,249,152 B

    decay_convert<<<M_TOT / 4, 256, 0, stream>>>(x, Wd, bd, decays, x_h);
    wcat_transpose<<<(NTOT * DM) / 256, 256, 0, stream>>>(Wi, Wa, Wcat_t);
    gemm_fused<<<dim3(M_TOT / 128, NTOT / 128), 256, 0, stream>>>(x_h, Wcat_t, bi, ba, out, angles);

    scan_sum1<<<BATCH * CHUNKS / 2, 256, 0, stream>>>(angles, decays, out, thetaC, hend, Dprod);
    scan_chunks<<<BATCH, 128, 0, stream>>>(thetaC, hend, Dprod, hentry);
    scan_final<<<BATCH * CHUNKS / 2, 256, 0, stream>>>(angles, decays, hentry, out);
}

// Round 5
// 221.391 us; speedup vs baseline: 1.0669x; 1.0669x over previous
//
#include <hip/hip_runtime.h>
#include <math.h>

typedef _Float16 half_t;
typedef __attribute__((ext_vector_type(8))) _Float16 half8;
typedef __attribute__((ext_vector_type(2))) _Float16 half2v;
typedef __attribute__((ext_vector_type(4))) float floatx4;

#define BATCH   8
#define SEQ     4096
#define DM      512
#define NP      256
#define M_TOT   32768
#define NTOT    768
#define CHUNKS  128
#define CHUNK_LEN 32

__device__ __forceinline__ void async_load16(const void* g, void* l) {
    __builtin_amdgcn_global_load_lds((const __attribute__((address_space(1))) void*)g,
                                     (__attribute__((address_space(3))) void*)l,
                                     16, 0, 0);
}

// ---------------------------------------------------------------------------
// decay + x fp32->fp16 convert. 2 rows per wave (64B/lane in flight).
// ---------------------------------------------------------------------------
__global__ __launch_bounds__(256) void decay_convert(const float* __restrict__ X,
                                                     const float* __restrict__ Wd,
                                                     const float* __restrict__ bd,
                                                     float* __restrict__ dec,
                                                     half_t* __restrict__ Xh) {
    const int wave = threadIdx.x >> 6;
    const int lane = threadIdx.x & 63;
    const int row0 = blockIdx.x * 8 + wave * 2;
    const float4* x0 = (const float4*)(X + (size_t)row0 * DM);
    const float4* x1 = x0 + 128;
    const float4* wd = (const float4*)Wd;
    float4 a0 = x0[2 * lane], a1 = x0[2 * lane + 1];
    float4 b0 = x1[2 * lane], b1 = x1[2 * lane + 1];
    float4 w0 = wd[2 * lane], w1 = wd[2 * lane + 1];
    float s0 = a0.x * w0.x + a0.y * w0.y + a0.z * w0.z + a0.w * w0.w
             + a1.x * w1.x + a1.y * w1.y + a1.z * w1.z + a1.w * w1.w;
    float s1 = b0.x * w0.x + b0.y * w0.y + b0.z * w0.z + b0.w * w0.w
             + b1.x * w1.x + b1.y * w1.y + b1.z * w1.z + b1.w * w1.w;
    half8 h0 = {(half_t)a0.x, (half_t)a0.y, (half_t)a0.z, (half_t)a0.w,
                (half_t)a1.x, (half_t)a1.y, (half_t)a1.z, (half_t)a1.w};
    half8 h1 = {(half_t)b0.x, (half_t)b0.y, (half_t)b0.z, (half_t)b0.w,
                (half_t)b1.x, (half_t)b1.y, (half_t)b1.z, (half_t)b1.w};
    *(half8*)(Xh + (size_t)row0 * DM + lane * 8) = h0;
    *(half8*)(Xh + (size_t)(row0 + 1) * DM + lane * 8) = h1;
#pragma unroll
    for (int off = 32; off > 0; off >>= 1) {
        s0 += __shfl_down(s0, off, 64);
        s1 += __shfl_down(s1, off, 64);
    }
    if (lane == 0) {
        dec[row0]     = 1.0f / (1.0f + __expf(-(s0 + bd[0])));
        dec[row0 + 1] = 1.0f / (1.0f + __expf(-(s1 + bd[0])));
    }
}

// ---------------------------------------------------------------------------
// Wcat_t[768][512] fp16 = [Wi^T ; Wa^T]
// ---------------------------------------------------------------------------
__global__ __launch_bounds__(256) void wcat_transpose(const float* __restrict__ Wi,
                                                      const float* __restrict__ Wa,
                                                      half_t* __restrict__ Wt) {
    const int idx = blockIdx.x * 256 + threadIdx.x;
    const int n = idx >> 9;
    const int k = idx & 511;
    float v = (n < DM) ? Wi[(size_t)k * DM + n] : Wa[(size_t)k * NP + (n - DM)];
    Wt[idx] = (half_t)v;
}

// ---------------------------------------------------------------------------
// Fused MFMA GEMM — round-3 proven version (BK=32, 16 KB LDS, 57 us).
// ---------------------------------------------------------------------------
__global__ __launch_bounds__(256) void gemm_fused(const half_t* __restrict__ Xh,
                                                  const half_t* __restrict__ Wt,
                                                  const float* __restrict__ bi,
                                                  const float* __restrict__ ba,
                                                  float* __restrict__ out,
                                                  half_t* __restrict__ angles) {
    __shared__ __align__(16) char As[8192];
    __shared__ __align__(16) char Bs[8192];

    const int bm   = blockIdx.x;
    const int bn   = blockIdx.y;
    const int tid  = threadIdx.x;
    const int wave = tid >> 6;
    const int lane = tid & 63;
    const int quad = lane >> 4;
    const int l16  = lane & 15;
    const int wrow = wave >> 1;
    const int wcol = wave & 1;

    floatx4 acc[4][4];
#pragma unroll
    for (int i = 0; i < 4; ++i)
#pragma unroll
        for (int j = 0; j < 4; ++j) acc[i][j] = (floatx4){0.f, 0.f, 0.f, 0.f};

    const int s0 = wave * 128 + lane;
    const int s1 = s0 + 64;
    const int r0 = s0 >> 2, kql0 = (s0 & 3) ^ ((r0 >> 1) & 3);
    const int r1 = s1 >> 2, kql1 = (s1 & 3) ^ ((r1 >> 1) & 3);
    const half_t* gA0 = Xh + (size_t)(bm * 128 + r0) * DM + kql0 * 8;
    const half_t* gA1 = Xh + (size_t)(bm * 128 + r1) * DM + kql1 * 8;
    const half_t* gB0 = Wt + (size_t)(bn * 128 + r0) * DM + kql0 * 8;
    const half_t* gB1 = Wt + (size_t)(bn * 128 + r1) * DM + kql1 * 8;
    char* lA0 = As + wave * 2048;
    char* lA1 = As + wave * 2048 + 1024;
    char* lB0 = Bs + wave * 2048;
    char* lB1 = Bs + wave * 2048 + 1024;

    for (int k0 = 0; k0 < DM; k0 += 32) {
        async_load16(gA0 + k0, lA0);
        async_load16(gA1 + k0, lA1);
        async_load16(gB0 + k0, lB0);
        async_load16(gB1 + k0, lB1);
        __syncthreads();

        half8 af[4], bf[4];
#pragma unroll
        for (int mt = 0; mt < 4; ++mt) {
            const int r = wrow * 64 + mt * 16 + l16;
            af[mt] = *(const half8*)(As + r * 64 + ((quad ^ ((r >> 1) & 3)) << 4));
        }
#pragma unroll
        for (int nt = 0; nt < 4; ++nt) {
            const int r = wcol * 64 + nt * 16 + l16;
            bf[nt] = *(const half8*)(Bs + r * 64 + ((quad ^ ((r >> 1) & 3)) << 4));
        }
#pragma unroll
        for (int mt = 0; mt < 4; ++mt)
#pragma unroll
            for (int nt = 0; nt < 4; ++nt)
                acc[mt][nt] = __builtin_amdgcn_mfma_f32_16x16x32_f16(af[mt], bf[nt],
                                                                     acc[mt][nt], 0, 0, 0);
        __syncthreads();
    }

    const int colbase = bn * 128 + wcol * 64;
#pragma unroll
    for (int nt = 0; nt < 4; ++nt) {
        const int col = colbase + nt * 16 + l16;
        const bool is_inj = col < DM;
        const float bias = is_inj ? bi[col] : ba[col - DM];
#pragma unroll
        for (int mt = 0; mt < 4; ++mt) {
            const int rowb = bm * 128 + wrow * 64 + mt * 16 + quad * 4;
#pragma unroll
            for (int r = 0; r < 4; ++r) {
                const float v = acc[mt][nt][r] + bias;
                const int row = rowb + r;
                if (is_inj) out[(size_t)row * DM + col] = v;
                else        angles[(size_t)row * NP + (col - DM)] = (half_t)v;
            }
        }
    }
}

// ---------------------------------------------------------------------------
// sum1: per-chunk summaries. 2 pairs/thread, 2 chunks/block. Software-
// pipelined in groups of 8 steps (next group's loads issued before current
// group's compute) for deep MLP.
// ---------------------------------------------------------------------------
__global__ __launch_bounds__(256) void scan_sum1(const half_t* __restrict__ angles,
                                                 const float* __restrict__ decays,
                                                 const float* __restrict__ inj,
                                                 float* __restrict__ thetaC,
                                                 float4* __restrict__ hend,
                                                 float* __restrict__ Dprod) {
    const int b   = blockIdx.x >> 6;
    const int sub = threadIdx.x >> 7;
    const int th  = threadIdx.x & 127;
    const int c   = (blockIdx.x & 63) * 2 + sub;
    const int p0  = th * 2;
    const int t0  = c * CHUNK_LEN;

    const half_t* ap = angles + (size_t)(b * SEQ + t0) * NP + p0;
    const float4* up = (const float4*)inj + (size_t)(b * SEQ + t0) * 128 + (p0 >> 1);
    const float*  dp = decays + b * SEQ + t0;

    half2v ab[2][8]; float4 ub[2][8]; float db[2][8];
#pragma unroll
    for (int j = 0; j < 8; ++j) {
        ab[0][j] = *(const half2v*)(ap + (size_t)j * NP);
        ub[0][j] = up[(size_t)j * 128];
        db[0][j] = dp[j];
    }

    float h0a = 0, h1a = 0, h0b = 0, h1b = 0, tha = 0, thb = 0, dc = 1.0f;
#pragma unroll
    for (int g = 0; g < 4; ++g) {
        const int cur = g & 1, nxt = cur ^ 1;
        if (g < 3) {
#pragma unroll
            for (int j = 0; j < 8; ++j) {
                const int t = (g + 1) * 8 + j;
                ab[nxt][j] = *(const half2v*)(ap + (size_t)t * NP);
                ub[nxt][j] = up[(size_t)t * 128];
                db[nxt][j] = dp[t];
            }
        }
#pragma unroll
        for (int j = 0; j < 8; ++j) {
            float a0 = (float)ab[cur][j][0], a1 = (float)ab[cur][j][1];
            float4 u = ub[cur][j];
            float d  = db[cur][j];
            float s0, c0, s1, c1;
            __sincosf(a0, &s0, &c0);
            __sincosf(a1, &s1, &c1);
            float n0a = fmaf(d, c0 * h0a - s0 * h1a, u.x);
            float n1a = fmaf(d, s0 * h0a + c0 * h1a, u.y);
            float n0b = fmaf(d, c1 * h0b - s1 * h1b, u.z);
            float n1b = fmaf(d, s1 * h0b + c1 * h1b, u.w);
            h0a = n0a; h1a = n1a; h0b = n0b; h1b = n1b;
            tha += a0; thb += a1; dc *= d;
        }
    }
    const size_t cbase = (size_t)(b * CHUNKS + c) * NP + p0;
    *(float2*)(thetaC + cbase) = make_float2(tha, thb);
    hend[cbase >> 1] = make_float4(h0a, h1a, h0b, h1b);
    if (th == 0) Dprod[b * CHUNKS + c] = dc;
}

// ---------------------------------------------------------------------------
// chunk-operator scan with 4-deep register prefetch (addresses scan-indep).
// ---------------------------------------------------------------------------
__global__ __launch_bounds__(128) void scan_chunks(const float* __restrict__ thetaC,
                                                   const float4* __restrict__ hend,
                                                   const float* __restrict__ Dprod,
                                                   float4* __restrict__ hentry) {
    const int b  = blockIdx.x;
    const int p0 = threadIdx.x * 2;
    const float2* tp = (const float2*)thetaC + (size_t)b * CHUNKS * 128 + (p0 >> 1);
    const float4* hp = hend + (size_t)b * CHUNKS * 128 + (p0 >> 1);
    float4*       ep = hentry + (size_t)b * CHUNKS * 128 + (p0 >> 1);
    const float*  Dp = Dprod + b * CHUNKS;

    float2 tb[2][4]; float4 hb[2][4]; float Db[2][4];
#pragma unroll
    for (int j = 0; j < 4; ++j) {
        tb[0][j] = tp[(size_t)j * 128];
        hb[0][j] = hp[(size_t)j * 128];
        Db[0][j] = Dp[j];
    }

    float h0a = 0, h1a = 0, h0b = 0, h1b = 0;
#pragma unroll
    for (int g = 0; g < 32; ++g) {
        const int cur = g & 1, nxt = cur ^ 1;
        if (g < 31) {
#pragma unroll
            for (int j = 0; j < 4; ++j) {
                const int c = (g + 1) * 4 + j;
                tb[nxt][j] = tp[(size_t)c * 128];
                hb[nxt][j] = hp[(size_t)c * 128];
                Db[nxt][j] = Dp[c];
            }
        }
#pragma unroll
        for (int j = 0; j < 4; ++j) {
            const int c = g * 4 + j;
            ep[(size_t)c * 128] = make_float4(h0a, h1a, h0b, h1b);
            float2 th2 = tb[cur][j];
            float4 he  = hb[cur][j];
            float D    = Db[cur][j];
            float s0, c0, s1, c1;
            __sincosf(th2.x, &s0, &c0);
            __sincosf(th2.y, &s1, &c1);
            float n0a = fmaf(D, c0 * h0a - s0 * h1a, he.x);
            float n1a = fmaf(D, s0 * h0a + c0 * h1a, he.y);
            float n0b = fmaf(D, c1 * h0b - s1 * h1b, he.z);
            float n1b = fmaf(D, s1 * h0b + c1 * h1b, he.w);
            h0a = n0a; h1a = n1a; h0b = n0b; h1b = n1b;
        }
    }
}

// ---------------------------------------------------------------------------
// final: redo local scan seeded with entry state; same pipelining; write out.
// ---------------------------------------------------------------------------
__global__ __launch_bounds__(256) void scan_final(const half_t* __restrict__ angles,
                                                  const float* __restrict__ decays,
                                                  const float4* __restrict__ hentry,
                                                  float* __restrict__ out) {
    const int b   = blockIdx.x >> 6;
    const int sub = threadIdx.x >> 7;
    const int th  = threadIdx.x & 127;
    const int c   = (blockIdx.x & 63) * 2 + sub;
    const int p0  = th * 2;
    const int t0  = c * CHUNK_LEN;

    const half_t* ap = angles + (size_t)(b * SEQ + t0) * NP + p0;
    float4*       op = (float4*)out + (size_t)(b * SEQ + t0) * 128 + (p0 >> 1);
    const float*  dp = decays + b * SEQ + t0;

    float4 v = hentry[(size_t)(b * CHUNKS + c) * 128 + (p0 >> 1)];
    float h0a = v.x, h1a = v.y, h0b = v.z, h1b = v.w;

    half2v ab[2][8]; float4 ub[2][8]; float db[2][8];
#pragma unroll
    for (int j = 0; j < 8; ++j) {
        ab[0][j] = *(const half2v*)(ap + (size_t)j * NP);
        ub[0][j] = op[(size_t)j * 128];
        db[0][j] = dp[j];
    }

#pragma unroll
    for (int g = 0; g < 4; ++g) {
        const int cur = g & 1, nxt = cur ^ 1;
        if (g < 3) {
#pragma unroll
            for (int j = 0; j < 8; ++j) {
                const int t = (g + 1) * 8 + j;
                ab[nxt][j] = *(const half2v*)(ap + (size_t)t * NP);
                ub[nxt][j] = op[(size_t)t * 128];
                db[nxt][j] = dp[t];
            }
        }
#pragma unroll
        for (int j = 0; j < 8; ++j) {
            const int t = g * 8 + j;
            float a0 = (float)ab[cur][j][0], a1 = (float)ab[cur][j][1];
            float4 u = ub[cur][j];
            float d  = db[cur][j];
            float s0, c0, s1, c1;
            __sincosf(a0, &s0, &c0);
            __sincosf(a1, &s1, &c1);
            float n0a = fmaf(d, c0 * h0a - s0 * h1a, u.x);
            float n1a = fmaf(d, s0 * h0a + c0 * h1a, u.y);
            float n0b = fmaf(d, c1 * h0b - s1 * h1b, u.z);
            float n1b = fmaf(d, s1 * h0b + c1 * h1b, u.w);
            h0a = n0a; h1a = n1a; h0b = n0b; h1b = n1b;
            op[(size_t)t * 128] = make_float4(h0a, h1a, h0b, h1b);
        }
    }
}

// ---------------------------------------------------------------------------
extern "C" void kernel_launch(void* const* d_in, const int* in_sizes, int n_in,
                              void* d_out, int out_size, void* d_ws, size_t ws_size,
                              hipStream_t stream) {
    const float* x  = (const float*)d_in[0];
    const float* Wa = (const float*)d_in[1];
    const float* ba = (const float*)d_in[2];
    const float* Wd = (const float*)d_in[3];
    const float* bd = (const float*)d_in[4];
    const float* Wi = (const float*)d_in[5];
    const float* bi = (const float*)d_in[6];
    float* out = (float*)d_out;

    char* ws = (char*)d_ws;
    half_t* x_h     = (half_t*)(ws);                  // 33,554,432 B @ 0
    float*  thetaC  = (float*)(ws);                   //  1,048,576 B (overlay)
    float4* hend    = (float4*)(ws + 1048576);        //  2,097,152 B (overlay)
    float*  Dprod   = (float*)(ws + 3145728);         //      4,096 B (overlay)
    float4* hentry  = (float4*)(ws + 3149824);        //  2,097,152 B (overlay)
    half_t* angles  = (half_t*)(ws + 33554432);       // 16,777,216 B
    float*  decays  = (float*)(ws + 50331648);        //    131,072 B
    half_t* Wcat_t  = (half_t*)(ws + 50462720);       //    786,432 B

    decay_convert<<<M_TOT / 8, 256, 0, stream>>>(x, Wd, bd, decays, x_h);
    wcat_transpose<<<(NTOT * DM) / 256, 256, 0, stream>>>(Wi, Wa, Wcat_t);
    gemm_fused<<<dim3(M_TOT / 128, NTOT / 128), 256, 0, stream>>>(x_h, Wcat_t, bi, ba, out, angles);

    scan_sum1<<<BATCH * CHUNKS / 2, 256, 0, stream>>>(angles, decays, out, thetaC, hend, Dprod);
    scan_chunks<<<BATCH, 128, 0, stream>>>(thetaC, hend, Dprod, hentry);
    scan_final<<<BATCH * CHUNKS / 2, 256, 0, stream>>>(angles, decays, hentry, out);
}